// Round 12
// baseline (11763.731 us; speedup 1.0000x reference)
//
#include <hip/hip_runtime.h>
#include <math.h>

#define BB 64
#define TT 256
#define VV 2000
#define EE 256
#define HD 256
#define ENC 256
#define AA 256
#define PP 512   // HI*WI = 16*32

#define S2L 2.8853900817779268f   // 2*log2(e)
#define SL  1.4426950408889634f   // log2(e)

// ---------------- helpers ----------------

typedef unsigned uvec4 __attribute__((ext_vector_type(4)));

__device__ __forceinline__ unsigned short f2h(float f) {
    _Float16 h = (_Float16)f; return __builtin_bit_cast(unsigned short, h);
}
// a += f16_lo(w) * x   (f32 accumulate)
__device__ __forceinline__ void fmlo(float& a, unsigned w, float x) {
    asm("v_fma_mix_f32 %0, %1, %2, %0 op_sel_hi:[1,0,0]" : "+v"(a) : "v"(w), "v"(x));
}
// a += f16_hi(w) * x
__device__ __forceinline__ void fmhi(float& a, unsigned w, float x) {
    asm("v_fma_mix_f32 %0, %1, %2, %0 op_sel:[1,0,0] op_sel_hi:[1,0,0]" : "+v"(a) : "v"(w), "v"(x));
}
// 8 MACs: w = 8 f16 weights, xa/xb = 8 fp32 x values
__device__ __forceinline__ void dot8m(float& a0, float& a1, uvec4 w, float4 xa, float4 xb) {
    fmlo(a0, w.x, xa.x); fmhi(a1, w.x, xa.y);
    fmlo(a0, w.y, xa.z); fmhi(a1, w.y, xa.w);
    fmlo(a0, w.z, xb.x); fmhi(a1, w.z, xb.y);
    fmlo(a0, w.w, xb.z); fmhi(a1, w.w, xb.w);
}
// 8 MACs into a single accumulator, x from pointer (uniform -> scalar loads)
__device__ __forceinline__ void dot8s(float& a, uvec4 w, const float* x) {
    fmlo(a, w.x, x[0]); fmhi(a, w.x, x[1]);
    fmlo(a, w.y, x[2]); fmhi(a, w.y, x[3]);
    fmlo(a, w.z, x[4]); fmhi(a, w.z, x[5]);
    fmlo(a, w.w, x[6]); fmhi(a, w.w, x[7]);
}
// fast tanh / sigmoid via v_exp_f32 (2^x) + v_rcp
__device__ __forceinline__ float ftanh(float x) {
    float u = __builtin_amdgcn_exp2f(x * S2L);
    return 1.f - 2.f * __builtin_amdgcn_rcpf(u + 1.f);
}
__device__ __forceinline__ float fsigm(float x) {
    float u = __builtin_amdgcn_exp2f(x * SL);
    return u * __builtin_amdgcn_rcpf(u + 1.f);
}

// ---------------- precompute kernels ----------------

__global__ void k_mean(const float* __restrict__ enc, float* __restrict__ meanb) {
    int b = blockIdx.x, c = threadIdx.x;
    const float4* p4 = reinterpret_cast<const float4*>(enc + ((size_t)b*ENC + c)*PP);
    float s = 0.f;
    for (int i = 0; i < PP/4; ++i) { float4 v = p4[i]; s += v.x + v.y + v.z + v.w; }
    meanb[b*ENC + c] = s * (1.0f/PP);
}

__global__ void k_init(const float* __restrict__ meanb,
                       const float* __restrict__ Winith, const float* __restrict__ binith,
                       const float* __restrict__ Winitc, const float* __restrict__ binitc,
                       float* __restrict__ h0, float* __restrict__ c0,
                       float* __restrict__ h1i, float* __restrict__ c1) {
    __shared__ float ms[ENC];
    int b = blockIdx.x, j = threadIdx.x;
    ms[j] = meanb[b*ENC + j];
    __syncthreads();
    float ah = binith[j], ac = binitc[j];
    const float4* wh = (const float4*)(Winith + (size_t)j*ENC);
    const float4* wc = (const float4*)(Winitc + (size_t)j*ENC);
    const float4* m4 = (const float4*)ms;
    for (int k = 0; k < ENC/4; ++k) {
        float4 m = m4[k], a = wh[k], b2 = wc[k];
        ah += a.x*m.x + a.y*m.y + a.z*m.z + a.w*m.w;
        ac += b2.x*m.x + b2.y*m.y + b2.z*m.z + b2.w*m.w;
    }
    float hv = tanhf(ah), cv = tanhf(ac);
    h0[b*HD + j] = hv; c0[b*HD + j] = cv;
    h1i[b*HD + j] = hv; c1[b*HD + j] = cv;
}

// att1T8[b][kk][p][j] (f16, PRE-SCALED by 2*log2e) with kk = a>>3, j = a&7
__global__ void k_att1T8(const float* __restrict__ enc, const float* __restrict__ Wae,
                         const float* __restrict__ bae, unsigned short* __restrict__ att1T8) {
    __shared__ float wsm[16][ENC];
    int a0 = blockIdx.x * 16, b = blockIdx.y, p = threadIdx.x;
    for (int i = threadIdx.x; i < 16*ENC; i += 512) wsm[i >> 8][i & 255] = Wae[(size_t)a0*ENC + i];
    __syncthreads();
    float acc[16];
    #pragma unroll
    for (int i = 0; i < 16; ++i) acc[i] = 0.f;
    const float* eb = enc + (size_t)b*ENC*PP + p;
    for (int c = 0; c < ENC; ++c) {
        float v = eb[(size_t)c*PP];
        #pragma unroll
        for (int i = 0; i < 16; ++i) acc[i] += v * wsm[i][c];
    }
    #pragma unroll
    for (int q = 0; q < 2; ++q) {
        unsigned short o[8];
        #pragma unroll
        for (int j = 0; j < 8; ++j) o[j] = f2h((acc[q*8+j] + bae[a0 + q*8 + j]) * S2L);
        *(uint4*)(att1T8 + (((size_t)b*32 + (a0 >> 3) + q)*PP + p)*8) = *(const uint4*)o;
    }
}

// encP[b][p][c] (f16) = enc[b][c][p] transposed
__global__ void k_encP(const float* __restrict__ enc, unsigned short* __restrict__ encP) {
    __shared__ float tile[256*33];
    int b = blockIdx.x, p0 = blockIdx.y * 32, tid = threadIdx.x;
    for (int i = tid; i < 256*32; i += 256) {
        int c = i >> 5, pl = i & 31;
        tile[c*33 + pl] = enc[((size_t)b*ENC + c)*PP + p0 + pl];
    }
    __syncthreads();
    for (int j = tid; j < 32*256; j += 256) {
        int p = j >> 8, c = j & 255;
        encP[((size_t)b*PP + p0 + p)*ENC + c] = f2h(tile[c*33 + p]);
    }
}

// W [N][K] fp32 -> WT8 [K/8][N][8] f16 (scaled)  (N = 1<<nsh)
__global__ void k_cvtT8(const float* __restrict__ src, unsigned short* __restrict__ dst,
                        int nsh, int kc, float scale) {
    int i = blockIdx.x*256 + threadIdx.x;
    int N = 1 << nsh;
    int kk = i >> nsh, n = i & (N - 1);
    const float* s = src + (size_t)n*(kc*8) + kk*8;
    unsigned short o[8];
    #pragma unroll
    for (int j = 0; j < 8; ++j) o[j] = f2h(s[j] * scale);
    *(uint4*)(dst + ((size_t)kk*N + n)*8) = *(const uint4*)o;
}

// Wout [2000][256] f32 -> WoT8 [32][2048][8] f16 (v padded to 2048 with zeros)
__global__ void k_cvtW(const float* __restrict__ src, unsigned short* __restrict__ dst) {
    int i = blockIdx.x*256 + threadIdx.x;   // 65536 total
    int kk = i >> 11, v = i & 2047;
    unsigned short o[8] = {0,0,0,0,0,0,0,0};
    if (v < VV) {
        const float* s = src + (size_t)v*HD + kk*8;
        #pragma unroll
        for (int j = 0; j < 8; ++j) o[j] = f2h(s[j]);
    }
    *(uint4*)(dst + ((size_t)kk*2048 + v)*8) = *(const uint4*)o;
}

// E[b][t][g] (f16) = sum_{k<256} Wih0[g][k] * emb[caps[b][t]][k]   (emb half of LSTM0 gates)
__global__ __launch_bounds__(1024) void k_E(const int* __restrict__ caps,
                                            const float* __restrict__ emb,
                                            const unsigned short* __restrict__ Wih0T8,
                                            unsigned short* __restrict__ E) {
    __shared__ float xs[16][256];
    __shared__ int cp[16];
    int b = blockIdx.x, tc = blockIdx.y, tid = threadIdx.x;
    if (tid < 16) cp[tid] = caps[b*TT + tc*16 + tid];
    __syncthreads();
    for (int i = tid; i < 16*256; i += 1024) {
        int r = i >> 8, c = i & 255;
        xs[r][c] = emb[(size_t)cp[r]*EE + c];
    }
    __syncthreads();
    const uvec4* wt = (const uvec4*)Wih0T8;
    float acc[16];
    #pragma unroll
    for (int r = 0; r < 16; ++r) acc[r] = 0.f;
    for (int kk = 0; kk < 32; ++kk) {
        uvec4 w = wt[(size_t)kk*1024 + tid];
        #pragma unroll
        for (int r = 0; r < 16; ++r) dot8s(acc[r], w, &xs[r][kk*8]);
    }
    #pragma unroll
    for (int r = 0; r < 16; ++r)
        E[((size_t)(b*TT + tc*16 + r))*1024 + tid] = f2h(acc[r]);
}

// ---------------- persistent per-batch-element main loop (no grid sync) ----------------

struct KP2 {
    const int* caps; const float* emb;
    const float* Wfa; const float* bfa; const float* bad;
    const float* bih0; const float* bhh0; const float* bih1; const float* bhh1;
    const unsigned short* WadT8;                       // [32][256][8], scaled by 2log2e
    const unsigned short* Wih0T8;                      // [64][1024][8]
    const unsigned short* Whh0T8;                      // [32][1024][8]
    const unsigned short* Wih1T8;                      // [32][1024][8]
    const unsigned short* Whh1T8;                      // [32][1024][8]
    const unsigned short* att1T8;                      // [b][32][512][8], scaled by 2log2e
    const unsigned short* encP;                        // [b][p][c]
    const unsigned short* E;                           // [b][t][1024] (may be unused)
    const float* h0g; const float* c0g; const float* h1g; const float* c1g;
    float* H1all; float* wsout;
};

template <int USEE>
__global__ __launch_bounds__(1024, 1) void main64(KP2 P) {
    __shared__ float att2s[AA];
    __shared__ float xt[512];            // [emb(256, only if !USEE) | ctx(256)] fp32
    __shared__ float h0s[HD], h1s[HD];   // fp32 state
    __shared__ float es[PP];
    __shared__ float red[2048];
    __shared__ float bs0[1024], bs1[1024];
    __shared__ float badS[AA], wfaS[AA];
    __shared__ float zinvS, bfaS, wfaSumS;

    const int b = blockIdx.x, tid = threadIdx.x;

    bs0[tid] = P.bih0[tid] + P.bhh0[tid];
    bs1[tid] = P.bih1[tid] + P.bhh1[tid];
    float c0r = 0.f, c1r = 0.f;
    if (tid < 256) {
        badS[tid] = P.bad[tid] * S2L;          // scaled: att2' = 2log2e * att2
        wfaS[tid] = P.Wfa[tid] * SL;           // scaled: log2e * wfa
        h0s[tid] = P.h0g[b*HD + tid]; h1s[tid] = P.h1g[b*HD + tid];
        c0r = P.c0g[b*HD + tid];      c1r = P.c1g[b*HD + tid];
    }
    if (tid == 0) bfaS = P.bfa[0] * SL;
    __syncthreads();
    if (tid == 0) {
        float s = 0.f;
        for (int i = 0; i < 256; ++i) s += wfaS[i];
        wfaSumS = s;
    }
    __syncthreads();

    const int p_sc = tid & 511, h_sc = tid >> 9;
    const int c2 = tid & 127, pq = tid >> 7;   // ctx mapping
    const uvec4* att1b = (const uvec4*)(P.att1T8 + (size_t)b*32*PP*8) + (size_t)(h_sc*16)*PP + p_sc;
    const unsigned short* Eb = P.E + (size_t)b*TT*1024;
    const unsigned* encPb = (const unsigned*)(P.encP + (size_t)b*PP*ENC);
    const uvec4* wadt = (const uvec4*)P.WadT8;
    const uvec4* wi0t = (const uvec4*)P.Wih0T8;
    const uvec4* wh0t = (const uvec4*)P.Whh0T8;
    const uvec4* wi1t = (const uvec4*)P.Wih1T8;
    const uvec4* wh1t = (const uvec4*)P.Whh1T8;

    for (int t = 0; t < TT; ++t) {
        // ---- P1: att2 partials (all threads) [+ emb prefetch if !USEE] ----
        {
            int a = tid & 255, kq = tid >> 8;
            const uvec4* w4 = wadt + (size_t)(kq*8)*256 + a;
            const float4* hv = (const float4*)h1s;
            float a0 = 0.f, a1 = 0.f;
            #pragma unroll
            for (int i = 0; i < 8; ++i) {
                uvec4 w = w4[(size_t)i*256];
                dot8m(a0, a1, w, hv[(kq*8 + i)*2], hv[(kq*8 + i)*2 + 1]);
            }
            red[kq*256 + a] = a0 + a1;
        }
        if (!USEE && tid < 256) {
            int cap = P.caps[b*TT + t];
            xt[tid] = P.emb[(size_t)cap*EE + tid];
        }
        __syncthreads();
        if (tid < 256) att2s[tid] = red[tid] + red[256+tid] + red[512+tid] + red[768+tid] + badS[tid];
        __syncthreads();

        // ---- P2: ctx-operand preload (32 regs) + score (heavy VALU hides the loads) ----
        unsigned ew[32];
        {
            #pragma unroll
            for (int i = 0; i < 32; ++i)
                ew[i] = __builtin_nontemporal_load(encPb + (size_t)(pq*64 + i)*128 + c2);

            float partial = 0.f;   // sum of wfa'[a]*r[a]; score' = wfaSum' - 2*partial
            #pragma unroll 4
            for (int i = 0; i < 16; ++i) {
                uvec4 w = __builtin_nontemporal_load(att1b + (size_t)i*PP);
                int ab = (h_sc*16 + i)*8;
                #pragma unroll
                for (int j = 0; j < 4; ++j) {
                    unsigned wj = w[j];
                    float a2l = att2s[ab + j*2], a2h = att2s[ab + j*2 + 1];
                    float x0, x1;
                    asm("v_fma_mix_f32 %0, %1, %2, %3 op_sel_hi:[1,0,0]"
                        : "=v"(x0) : "v"(wj), "v"(1.0f), "v"(a2l));
                    asm("v_fma_mix_f32 %0, %1, %2, %3 op_sel:[1,0,0] op_sel_hi:[1,0,0]"
                        : "=v"(x1) : "v"(wj), "v"(1.0f), "v"(a2h));
                    float r0 = __builtin_amdgcn_rcpf(__builtin_amdgcn_exp2f(x0) + 1.f);
                    float r1 = __builtin_amdgcn_rcpf(__builtin_amdgcn_exp2f(x1) + 1.f);
                    partial = fmaf(wfaS[ab + j*2],     r0, partial);
                    partial = fmaf(wfaS[ab + j*2 + 1], r1, partial);
                }
            }
            red[h_sc*512 + p_sc] = partial;
        }
        __syncthreads();
        if (tid < 512)
            es[tid] = __builtin_amdgcn_exp2f(wfaSumS - 2.f*(red[tid] + red[512 + tid]) + bfaS);
        __syncthreads();

        // ---- P3: Z (wave 0) + ctx partials (regs for first half, stream second half) ----
        if (tid < 64) {
            float z = 0.f;
            #pragma unroll
            for (int i = 0; i < 8; ++i) z += es[tid*8 + i];
            for (int o = 32; o > 0; o >>= 1) z += __shfl_down(z, o, 64);
            if (tid == 0) zinvS = 1.f / z;
        }
        {
            float a0 = 0.f, a1 = 0.f;
            #pragma unroll
            for (int i = 0; i < 32; ++i) {
                float e = es[pq*64 + i];
                fmlo(a0, ew[i], e); fmhi(a1, ew[i], e);
            }
            #pragma unroll 8
            for (int i = 32; i < 64; ++i) {
                unsigned w2 = __builtin_nontemporal_load(encPb + (size_t)(pq*64 + i)*128 + c2);
                float e = es[pq*64 + i];
                fmlo(a0, w2, e); fmhi(a1, w2, e);
            }
            red[pq*256 + c2*2]     = a0;
            red[pq*256 + c2*2 + 1] = a1;
        }
        __syncthreads();
        // assemble: ctx (tid<256) -> xt[256..512], ws out (512..1024)
        if (tid < 256) {
            float s = 0.f;
            #pragma unroll
            for (int q = 0; q < 8; ++q) s += red[q*256 + tid];
            xt[256 + tid] = s * zinvS;
        } else if (tid >= 512) {
            int p = tid - 512;
            P.wsout[((size_t)b*TT + t)*PP + p] = es[p] * zinvS;
        }
        __syncthreads();

        // ---- P4: LSTM0 gate g = tid ----
        {
            float a0 = bs0[tid], a1 = 0.f;
            if (USEE) {
                unsigned short eu = Eb[(size_t)t*1024 + tid];
                a0 += (float)__builtin_bit_cast(_Float16, eu);
            }
            const uvec4* wi = wi0t + tid;
            const float4* xv = (const float4*)xt;
            if (USEE) {
                #pragma unroll 8
                for (int kk = 32; kk < 64; ++kk) {
                    uvec4 w = wi[(size_t)kk*1024];
                    dot8m(a0, a1, w, xv[kk*2], xv[kk*2 + 1]);
                }
            } else {
                #pragma unroll 8
                for (int kk = 0; kk < 64; ++kk) {
                    uvec4 w = wi[(size_t)kk*1024];
                    dot8m(a0, a1, w, xv[kk*2], xv[kk*2 + 1]);
                }
            }
            const uvec4* wh = wh0t + tid;
            const float4* hv = (const float4*)h0s;
            #pragma unroll 8
            for (int kk = 0; kk < 32; ++kk) {
                uvec4 w = wh[(size_t)kk*1024];
                dot8m(a0, a1, w, hv[kk*2], hv[kk*2 + 1]);
            }
            red[tid] = a0 + a1;
        }
        __syncthreads();
        if (tid < 256) {
            float gi = red[tid], gf = red[HD+tid], gg = red[2*HD+tid], go = red[3*HD+tid];
            c0r = fsigm(gf)*c0r + fsigm(gi)*ftanh(gg);
            h0s[tid] = fsigm(go)*ftanh(c0r);
        }
        __syncthreads();

        // ---- P5: LSTM1 gate g = tid ----
        {
            float a0 = bs1[tid], a1 = 0.f;
            const uvec4* wi = wi1t + tid;
            const float4* hv0 = (const float4*)h0s;
            #pragma unroll 8
            for (int kk = 0; kk < 32; ++kk) {
                uvec4 w = wi[(size_t)kk*1024];
                dot8m(a0, a1, w, hv0[kk*2], hv0[kk*2 + 1]);
            }
            const uvec4* wh = wh1t + tid;
            const float4* hv1 = (const float4*)h1s;
            #pragma unroll 8
            for (int kk = 0; kk < 32; ++kk) {
                uvec4 w = wh[(size_t)kk*1024];
                dot8m(a0, a1, w, hv1[kk*2], hv1[kk*2 + 1]);
            }
            red[tid] = a0 + a1;
        }
        __syncthreads();
        if (tid < 256) {
            float gi = red[tid], gf = red[HD+tid], gg = red[2*HD+tid], go = red[3*HD+tid];
            c1r = fsigm(gf)*c1r + fsigm(gi)*ftanh(gg);
            float h = fsigm(go)*ftanh(c1r);
            h1s[tid] = h;
            P.H1all[((size_t)t*BB + b)*HD + tid] = h;
        }
        __syncthreads();
    }
}

// ---------------- finalization: out = H1all @ WoutT + bout ----------------
// thread = 1 v-column, 32 rows; H-row operands are wave-uniform -> scalar loads.

__global__ __launch_bounds__(256)
void f2o(const float* __restrict__ H1all, const unsigned short* __restrict__ WoT8,
         const float* __restrict__ bout, float* __restrict__ out0) {
    int vt = blockIdx.x, rt = blockIdx.y, tid = threadIdx.x;
    int v = vt*256 + tid;
    const float* Hrow = H1all + (size_t)rt*32*HD;
    const uvec4* wt = (const uvec4*)WoT8;
    float acc[32];
    #pragma unroll
    for (int r = 0; r < 32; ++r) acc[r] = 0.f;
    for (int kk = 0; kk < 32; ++kk) {
        uvec4 w = wt[(size_t)kk*2048 + v];
        #pragma unroll
        for (int r = 0; r < 32; ++r) dot8s(acc[r], w, Hrow + r*HD + kk*8);
    }
    if (v < VV) {
        float bv = bout[v];
        #pragma unroll
        for (int r = 0; r < 32; ++r) {
            int row = rt*32 + r, tt = row >> 6, bb = row & 63;
            out0[((size_t)bb*TT + tt)*VV + v] = acc[r] + bv;
        }
    }
}

// ---------------- host ----------------

extern "C" void kernel_launch(void* const* d_in, const int* in_sizes, int n_in,
                              void* d_out, int out_size, void* d_ws, size_t ws_size,
                              hipStream_t stream) {
    const float* enc    = (const float*)d_in[0];
    const int*   caps   = (const int*)  d_in[1];
    const float* emb    = (const float*)d_in[2];
    const float* Wae    = (const float*)d_in[3];
    const float* bae    = (const float*)d_in[4];
    const float* Wad    = (const float*)d_in[5];
    const float* bad    = (const float*)d_in[6];
    const float* Wfa    = (const float*)d_in[7];
    const float* bfa    = (const float*)d_in[8];
    const float* Winith = (const float*)d_in[9];
    const float* binith = (const float*)d_in[10];
    const float* Winitc = (const float*)d_in[11];
    const float* binitc = (const float*)d_in[12];
    const float* Wih0   = (const float*)d_in[13];
    const float* Whh0   = (const float*)d_in[14];
    const float* bih0   = (const float*)d_in[15];
    const float* bhh0   = (const float*)d_in[16];
    const float* Wih1   = (const float*)d_in[17];
    const float* Whh1   = (const float*)d_in[18];
    const float* bih1   = (const float*)d_in[19];
    const float* bhh1   = (const float*)d_in[20];
    const float* Wout   = (const float*)d_in[21];
    const float* bout   = (const float*)d_in[22];

    // workspace layout (float units)
    float* ws = (float*)d_ws;
    unsigned short* att1T8 = (unsigned short*)(ws);             // 8,388,608 ush
    unsigned short* encP   = (unsigned short*)(ws + 4194304);   // 8,388,608 ush
    float* H1all = ws + 8388608;                                // 4,194,304 f
    unsigned short* Wih0T8 = (unsigned short*)(ws + 12582912);  //   524,288 ush
    unsigned short* Whh0T8 = (unsigned short*)(ws + 12845056);  //   262,144 ush
    unsigned short* Wih1T8 = (unsigned short*)(ws + 12976128);  //   262,144 ush
    unsigned short* Whh1T8 = (unsigned short*)(ws + 13107200);  //   262,144 ush
    unsigned short* WadT8  = (unsigned short*)(ws + 13238272);  //    65,536 ush
    float* meanb = ws + 13271040;
    float* h0g   = ws + 13287424;
    float* c0g   = ws + 13303808;
    float* h1g   = ws + 13320192;
    float* c1g   = ws + 13336576;
    unsigned short* E = (unsigned short*)(ws + 13352960);       // 16,777,216 ush (optional)

    const int useE = (ws_size >= (size_t)(13352960 + 8388608) * 4) ? 1 : 0;
    // WoutT8: 524,288 ush = 262,144 floats
    const int useWtail = (ws_size >= (size_t)(13352960 + 8388608 + 262144) * 4) ? 1 : 0;
    unsigned short* WoT8 = useWtail ? (unsigned short*)(ws + 13352960 + 8388608)
                                    : att1T8;   // reuse att1 region after main64

    float* out0  = (float*)d_out;
    float* wsout = out0 + (size_t)BB*TT*VV;

    hipLaunchKernelGGL(k_mean,   dim3(BB),     dim3(256), 0, stream, enc, meanb);
    hipLaunchKernelGGL(k_init,   dim3(BB),     dim3(256), 0, stream, meanb, Winith, binith,
                       Winitc, binitc, h0g, c0g, h1g, c1g);
    hipLaunchKernelGGL(k_att1T8, dim3(16, BB), dim3(512), 0, stream, enc, Wae, bae, att1T8);
    hipLaunchKernelGGL(k_encP,   dim3(BB, 16), dim3(256), 0, stream, enc, encP);
    hipLaunchKernelGGL(k_cvtT8,  dim3(256),    dim3(256), 0, stream, Wih0, Wih0T8, 10, 64, 1.0f);
    hipLaunchKernelGGL(k_cvtT8,  dim3(128),    dim3(256), 0, stream, Whh0, Whh0T8, 10, 32, 1.0f);
    hipLaunchKernelGGL(k_cvtT8,  dim3(128),    dim3(256), 0, stream, Wih1, Wih1T8, 10, 32, 1.0f);
    hipLaunchKernelGGL(k_cvtT8,  dim3(128),    dim3(256), 0, stream, Whh1, Whh1T8, 10, 32, 1.0f);
    hipLaunchKernelGGL(k_cvtT8,  dim3(32),     dim3(256), 0, stream, Wad,  WadT8,   8, 32, S2L);
    if (useE)
        hipLaunchKernelGGL(k_E,  dim3(BB, 16), dim3(1024), 0, stream, caps, emb, Wih0T8, E);
    if (useWtail)
        hipLaunchKernelGGL(k_cvtW, dim3(256),  dim3(256), 0, stream, Wout, WoT8);

    KP2 kp;
    kp.caps = caps; kp.emb = emb;
    kp.Wfa = Wfa; kp.bfa = bfa; kp.bad = bad;
    kp.bih0 = bih0; kp.bhh0 = bhh0; kp.bih1 = bih1; kp.bhh1 = bhh1;
    kp.WadT8 = WadT8; kp.Wih0T8 = Wih0T8; kp.Whh0T8 = Whh0T8; kp.Wih1T8 = Wih1T8; kp.Whh1T8 = Whh1T8;
    kp.att1T8 = att1T8; kp.encP = encP; kp.E = E;
    kp.h0g = h0g; kp.c0g = c0g; kp.h1g = h1g; kp.c1g = c1g;
    kp.H1all = H1all; kp.wsout = wsout;

    if (useE)
        hipLaunchKernelGGL((main64<1>), dim3(BB), dim3(1024), 0, stream, kp);
    else
        hipLaunchKernelGGL((main64<0>), dim3(BB), dim3(1024), 0, stream, kp);

    if (!useWtail)
        hipLaunchKernelGGL(k_cvtW, dim3(256),  dim3(256), 0, stream, Wout, WoT8);

    hipLaunchKernelGGL(f2o, dim3(8, 512), dim3(256), 0, stream, H1all, WoT8, bout, out0);
}

// Round 13
// 10100.723 us; speedup vs baseline: 1.1646x; 1.1646x over previous
//
#include <hip/hip_runtime.h>
#include <math.h>

#define BB 64
#define TT 256
#define VV 2000
#define EE 256
#define HD 256
#define ENC 256
#define AA 256
#define PP 512   // HI*WI = 16*32

#define S2L 2.8853900817779268f   // 2*log2(e)
#define SL  1.4426950408889634f   // log2(e)

// ---------------- helpers ----------------

typedef unsigned uvec4 __attribute__((ext_vector_type(4)));

__device__ __forceinline__ unsigned short f2h(float f) {
    _Float16 h = (_Float16)f; return __builtin_bit_cast(unsigned short, h);
}
// a += f16_lo(w) * x   (f32 accumulate)
__device__ __forceinline__ void fmlo(float& a, unsigned w, float x) {
    asm("v_fma_mix_f32 %0, %1, %2, %0 op_sel_hi:[1,0,0]" : "+v"(a) : "v"(w), "v"(x));
}
// a += f16_hi(w) * x
__device__ __forceinline__ void fmhi(float& a, unsigned w, float x) {
    asm("v_fma_mix_f32 %0, %1, %2, %0 op_sel:[1,0,0] op_sel_hi:[1,0,0]" : "+v"(a) : "v"(w), "v"(x));
}
// 8 MACs: w = 8 f16 weights, xa/xb = 8 fp32 x values
__device__ __forceinline__ void dot8m(float& a0, float& a1, uvec4 w, float4 xa, float4 xb) {
    fmlo(a0, w.x, xa.x); fmhi(a1, w.x, xa.y);
    fmlo(a0, w.y, xa.z); fmhi(a1, w.y, xa.w);
    fmlo(a0, w.z, xb.x); fmhi(a1, w.z, xb.y);
    fmlo(a0, w.w, xb.z); fmhi(a1, w.w, xb.w);
}
// 8 MACs into a single accumulator, x from pointer (uniform -> scalar loads)
__device__ __forceinline__ void dot8s(float& a, uvec4 w, const float* x) {
    fmlo(a, w.x, x[0]); fmhi(a, w.x, x[1]);
    fmlo(a, w.y, x[2]); fmhi(a, w.y, x[3]);
    fmlo(a, w.z, x[4]); fmhi(a, w.z, x[5]);
    fmlo(a, w.w, x[6]); fmhi(a, w.w, x[7]);
}
// fast tanh / sigmoid via v_exp_f32 (2^x) + v_rcp
__device__ __forceinline__ float ftanh(float x) {
    float u = __builtin_amdgcn_exp2f(x * S2L);
    return 1.f - 2.f * __builtin_amdgcn_rcpf(u + 1.f);
}
__device__ __forceinline__ float fsigm(float x) {
    float u = __builtin_amdgcn_exp2f(x * SL);
    return u * __builtin_amdgcn_rcpf(u + 1.f);
}

// ---------------- precompute kernels ----------------

__global__ void k_mean(const float* __restrict__ enc, float* __restrict__ meanb) {
    int b = blockIdx.x, c = threadIdx.x;
    const float4* p4 = reinterpret_cast<const float4*>(enc + ((size_t)b*ENC + c)*PP);
    float s = 0.f;
    for (int i = 0; i < PP/4; ++i) { float4 v = p4[i]; s += v.x + v.y + v.z + v.w; }
    meanb[b*ENC + c] = s * (1.0f/PP);
}

__global__ void k_init(const float* __restrict__ meanb,
                       const float* __restrict__ Winith, const float* __restrict__ binith,
                       const float* __restrict__ Winitc, const float* __restrict__ binitc,
                       float* __restrict__ h0, float* __restrict__ c0,
                       float* __restrict__ h1i, float* __restrict__ c1) {
    __shared__ float ms[ENC];
    int b = blockIdx.x, j = threadIdx.x;
    ms[j] = meanb[b*ENC + j];
    __syncthreads();
    float ah = binith[j], ac = binitc[j];
    const float4* wh = (const float4*)(Winith + (size_t)j*ENC);
    const float4* wc = (const float4*)(Winitc + (size_t)j*ENC);
    const float4* m4 = (const float4*)ms;
    for (int k = 0; k < ENC/4; ++k) {
        float4 m = m4[k], a = wh[k], b2 = wc[k];
        ah += a.x*m.x + a.y*m.y + a.z*m.z + a.w*m.w;
        ac += b2.x*m.x + b2.y*m.y + b2.z*m.z + b2.w*m.w;
    }
    float hv = tanhf(ah), cv = tanhf(ac);
    h0[b*HD + j] = hv; c0[b*HD + j] = cv;
    h1i[b*HD + j] = hv; c1[b*HD + j] = cv;
}

// att1T8[b][kk][p][j] (f16, PRE-SCALED by 2*log2e) with kk = a>>3, j = a&7
__global__ void k_att1T8(const float* __restrict__ enc, const float* __restrict__ Wae,
                         const float* __restrict__ bae, unsigned short* __restrict__ att1T8) {
    __shared__ float wsm[16][ENC];
    int a0 = blockIdx.x * 16, b = blockIdx.y, p = threadIdx.x;
    for (int i = threadIdx.x; i < 16*ENC; i += 512) wsm[i >> 8][i & 255] = Wae[(size_t)a0*ENC + i];
    __syncthreads();
    float acc[16];
    #pragma unroll
    for (int i = 0; i < 16; ++i) acc[i] = 0.f;
    const float* eb = enc + (size_t)b*ENC*PP + p;
    for (int c = 0; c < ENC; ++c) {
        float v = eb[(size_t)c*PP];
        #pragma unroll
        for (int i = 0; i < 16; ++i) acc[i] += v * wsm[i][c];
    }
    #pragma unroll
    for (int q = 0; q < 2; ++q) {
        unsigned short o[8];
        #pragma unroll
        for (int j = 0; j < 8; ++j) o[j] = f2h((acc[q*8+j] + bae[a0 + q*8 + j]) * S2L);
        *(uint4*)(att1T8 + (((size_t)b*32 + (a0 >> 3) + q)*PP + p)*8) = *(const uint4*)o;
    }
}

// encP[b][p][c] (f16) = enc[b][c][p] transposed
__global__ void k_encP(const float* __restrict__ enc, unsigned short* __restrict__ encP) {
    __shared__ float tile[256*33];
    int b = blockIdx.x, p0 = blockIdx.y * 32, tid = threadIdx.x;
    for (int i = tid; i < 256*32; i += 256) {
        int c = i >> 5, pl = i & 31;
        tile[c*33 + pl] = enc[((size_t)b*ENC + c)*PP + p0 + pl];
    }
    __syncthreads();
    for (int j = tid; j < 32*256; j += 256) {
        int p = j >> 8, c = j & 255;
        encP[((size_t)b*PP + p0 + p)*ENC + c] = f2h(tile[c*33 + p]);
    }
}

// W [N][K] fp32 -> WT8 [K/8][N][8] f16 (scaled)  (N = 1<<nsh)
__global__ void k_cvtT8(const float* __restrict__ src, unsigned short* __restrict__ dst,
                        int nsh, int kc, float scale) {
    int i = blockIdx.x*256 + threadIdx.x;
    int N = 1 << nsh;
    int kk = i >> nsh, n = i & (N - 1);
    const float* s = src + (size_t)n*(kc*8) + kk*8;
    unsigned short o[8];
    #pragma unroll
    for (int j = 0; j < 8; ++j) o[j] = f2h(s[j] * scale);
    *(uint4*)(dst + ((size_t)kk*N + n)*8) = *(const uint4*)o;
}

// Wout [2000][256] f32 -> WoT8 [32][2048][8] f16 (v padded to 2048 with zeros)
__global__ void k_cvtW(const float* __restrict__ src, unsigned short* __restrict__ dst) {
    int i = blockIdx.x*256 + threadIdx.x;   // 65536 total
    int kk = i >> 11, v = i & 2047;
    unsigned short o[8] = {0,0,0,0,0,0,0,0};
    if (v < VV) {
        const float* s = src + (size_t)v*HD + kk*8;
        #pragma unroll
        for (int j = 0; j < 8; ++j) o[j] = f2h(s[j]);
    }
    *(uint4*)(dst + ((size_t)kk*2048 + v)*8) = *(const uint4*)o;
}

// E[b][t][g] (f16) = sum_{k<256} Wih0[g][k] * emb[caps[b][t]][k]   (emb half of LSTM0 gates)
__global__ __launch_bounds__(1024) void k_E(const int* __restrict__ caps,
                                            const float* __restrict__ emb,
                                            const unsigned short* __restrict__ Wih0T8,
                                            unsigned short* __restrict__ E) {
    __shared__ float xs[16][256];
    __shared__ int cp[16];
    int b = blockIdx.x, tc = blockIdx.y, tid = threadIdx.x;
    if (tid < 16) cp[tid] = caps[b*TT + tc*16 + tid];
    __syncthreads();
    for (int i = tid; i < 16*256; i += 1024) {
        int r = i >> 8, c = i & 255;
        xs[r][c] = emb[(size_t)cp[r]*EE + c];
    }
    __syncthreads();
    const uvec4* wt = (const uvec4*)Wih0T8;
    float acc[16];
    #pragma unroll
    for (int r = 0; r < 16; ++r) acc[r] = 0.f;
    for (int kk = 0; kk < 32; ++kk) {
        uvec4 w = wt[(size_t)kk*1024 + tid];
        #pragma unroll
        for (int r = 0; r < 16; ++r) dot8s(acc[r], w, &xs[r][kk*8]);
    }
    #pragma unroll
    for (int r = 0; r < 16; ++r)
        E[((size_t)(b*TT + tc*16 + r))*1024 + tid] = f2h(acc[r]);
}

// ---------------- persistent per-batch-element main loop (no grid sync) ----------------

struct KP2 {
    const int* caps; const float* emb;
    const float* Wfa; const float* bfa; const float* bad;
    const float* bih0; const float* bhh0; const float* bih1; const float* bhh1;
    const unsigned short* WadT8;                       // [32][256][8], scaled by 2log2e
    const unsigned short* Wih0T8;                      // [64][1024][8]
    const unsigned short* Whh0T8;                      // [32][1024][8]
    const unsigned short* Wih1T8;                      // [32][1024][8]
    const unsigned short* Whh1T8;                      // [32][1024][8]
    const unsigned short* att1T8;                      // [b][32][512][8], scaled by 2log2e
    const unsigned short* encP;                        // [b][p][c]
    const unsigned short* E;                           // [b][t][1024] (may be unused)
    const float* h0g; const float* c0g; const float* h1g; const float* c1g;
    float* H1all; float* wsout;
};

template <int USEE>
__global__ __launch_bounds__(1024, 1) void main64(KP2 P) {
    __shared__ float att2s[AA];
    __shared__ float xt[512];            // [emb(256, only if !USEE) | ctx(256)] fp32
    __shared__ float h0s[HD], h1s[HD];   // fp32 state
    __shared__ float es[PP];
    __shared__ float red[2048];
    __shared__ float bs0[1024], bs1[1024];
    __shared__ float badS[AA], wfaS[AA];
    __shared__ float zinvS, bfaS, wfaSumS;

    const int b = blockIdx.x, tid = threadIdx.x;

    bs0[tid] = P.bih0[tid] + P.bhh0[tid];
    bs1[tid] = P.bih1[tid] + P.bhh1[tid];
    float c0r = 0.f, c1r = 0.f;
    if (tid < 256) {
        badS[tid] = P.bad[tid] * S2L;          // scaled: att2' = 2log2e * att2
        wfaS[tid] = P.Wfa[tid] * SL;           // scaled: log2e * wfa
        h0s[tid] = P.h0g[b*HD + tid]; h1s[tid] = P.h1g[b*HD + tid];
        c0r = P.c0g[b*HD + tid];      c1r = P.c1g[b*HD + tid];
    }
    if (tid == 0) bfaS = P.bfa[0] * SL;
    __syncthreads();
    if (tid == 0) {
        float s = 0.f;
        for (int i = 0; i < 256; ++i) s += wfaS[i];
        wfaSumS = s;
    }
    __syncthreads();

    const int p_sc = tid & 511, h_sc = tid >> 9;
    const uvec4* att1b = (const uvec4*)(P.att1T8 + (size_t)b*32*PP*8) + (size_t)(h_sc*16)*PP + p_sc;
    const unsigned short* Eb = P.E + (size_t)b*TT*1024;
    const unsigned* encPb = (const unsigned*)(P.encP + (size_t)b*PP*ENC);
    const uvec4* wadt = (const uvec4*)P.WadT8;
    const uvec4* wi0t = (const uvec4*)P.Wih0T8;
    const uvec4* wh0t = (const uvec4*)P.Whh0T8;
    const uvec4* wi1t = (const uvec4*)P.Wih1T8;
    const uvec4* wh1t = (const uvec4*)P.Whh1T8;

    for (int t = 0; t < TT; ++t) {
        // ---- P1: att2 partials (all threads) [+ emb prefetch if !USEE] ----
        {
            int a = tid & 255, kq = tid >> 8;
            const uvec4* w4 = wadt + (size_t)(kq*8)*256 + a;
            const float4* hv = (const float4*)h1s;
            float a0 = 0.f, a1 = 0.f;
            #pragma unroll
            for (int i = 0; i < 8; ++i) {
                uvec4 w = w4[(size_t)i*256];
                dot8m(a0, a1, w, hv[(kq*8 + i)*2], hv[(kq*8 + i)*2 + 1]);
            }
            red[kq*256 + a] = a0 + a1;
        }
        if (!USEE && tid < 256) {
            int cap = P.caps[b*TT + t];
            xt[tid] = P.emb[(size_t)cap*EE + tid];
        }
        __syncthreads();
        if (tid < 256) att2s[tid] = red[tid] + red[256+tid] + red[512+tid] + red[768+tid] + badS[tid];
        __syncthreads();

        // ---- P2: score, streamed att1 (nontemporal), exp2-domain math ----
        {
            float partial = 0.f;   // sum of wfa'[a]*r[a]; score' = wfaSum' - 2*partial
            #pragma unroll 4
            for (int i = 0; i < 16; ++i) {
                uvec4 w = __builtin_nontemporal_load(att1b + (size_t)i*PP);
                int ab = (h_sc*16 + i)*8;
                #pragma unroll
                for (int j = 0; j < 4; ++j) {
                    unsigned wj = w[j];
                    float a2l = att2s[ab + j*2], a2h = att2s[ab + j*2 + 1];
                    float x0, x1;
                    asm("v_fma_mix_f32 %0, %1, %2, %3 op_sel_hi:[1,0,0]"
                        : "=v"(x0) : "v"(wj), "v"(1.0f), "v"(a2l));
                    asm("v_fma_mix_f32 %0, %1, %2, %3 op_sel:[1,0,0] op_sel_hi:[1,0,0]"
                        : "=v"(x1) : "v"(wj), "v"(1.0f), "v"(a2h));
                    float r0 = __builtin_amdgcn_rcpf(__builtin_amdgcn_exp2f(x0) + 1.f);
                    float r1 = __builtin_amdgcn_rcpf(__builtin_amdgcn_exp2f(x1) + 1.f);
                    partial = fmaf(wfaS[ab + j*2],     r0, partial);
                    partial = fmaf(wfaS[ab + j*2 + 1], r1, partial);
                }
            }
            red[h_sc*512 + p_sc] = partial;
        }
        __syncthreads();
        if (tid < 512)
            es[tid] = __builtin_amdgcn_exp2f(wfaSumS - 2.f*(red[tid] + red[512 + tid]) + bfaS);
        __syncthreads();

        // ---- P3: Z (wave 0) + ctx partials (all) ----
        if (tid < 64) {
            float z = 0.f;
            #pragma unroll
            for (int i = 0; i < 8; ++i) z += es[tid*8 + i];
            for (int o = 32; o > 0; o >>= 1) z += __shfl_down(z, o, 64);
            if (tid == 0) zinvS = 1.f / z;
        }
        {
            int c2 = tid & 127, pq = tid >> 7;
            float a0 = 0.f, a1 = 0.f;
            #pragma unroll 8
            for (int i = 0; i < 64; ++i) {
                int p = pq*64 + i;
                unsigned w = __builtin_nontemporal_load(encPb + (size_t)p*128 + c2);
                float e = es[p];
                fmlo(a0, w, e); fmhi(a1, w, e);
            }
            red[pq*256 + c2*2]     = a0;
            red[pq*256 + c2*2 + 1] = a1;
        }
        __syncthreads();
        // assemble: ctx (tid<256) -> xt[256..512], ws out (512..1024)
        if (tid < 256) {
            float s = 0.f;
            #pragma unroll
            for (int q = 0; q < 8; ++q) s += red[q*256 + tid];
            xt[256 + tid] = s * zinvS;
        } else if (tid >= 512) {
            int p = tid - 512;
            P.wsout[((size_t)b*TT + t)*PP + p] = es[p] * zinvS;
        }
        __syncthreads();

        // ---- P4: LSTM0 gate g = tid ----
        {
            float a0 = bs0[tid], a1 = 0.f;
            if (USEE) {
                unsigned short eu = Eb[(size_t)t*1024 + tid];
                a0 += (float)__builtin_bit_cast(_Float16, eu);
            }
            const uvec4* wi = wi0t + tid;
            const float4* xv = (const float4*)xt;
            if (USEE) {
                #pragma unroll 8
                for (int kk = 32; kk < 64; ++kk) {
                    uvec4 w = wi[(size_t)kk*1024];
                    dot8m(a0, a1, w, xv[kk*2], xv[kk*2 + 1]);
                }
            } else {
                #pragma unroll 8
                for (int kk = 0; kk < 64; ++kk) {
                    uvec4 w = wi[(size_t)kk*1024];
                    dot8m(a0, a1, w, xv[kk*2], xv[kk*2 + 1]);
                }
            }
            const uvec4* wh = wh0t + tid;
            const float4* hv = (const float4*)h0s;
            #pragma unroll 8
            for (int kk = 0; kk < 32; ++kk) {
                uvec4 w = wh[(size_t)kk*1024];
                dot8m(a0, a1, w, hv[kk*2], hv[kk*2 + 1]);
            }
            red[tid] = a0 + a1;
        }
        __syncthreads();
        if (tid < 256) {
            float gi = red[tid], gf = red[HD+tid], gg = red[2*HD+tid], go = red[3*HD+tid];
            c0r = fsigm(gf)*c0r + fsigm(gi)*ftanh(gg);
            h0s[tid] = fsigm(go)*ftanh(c0r);
        }
        __syncthreads();

        // ---- P5: LSTM1 gate g = tid ----
        {
            float a0 = bs1[tid], a1 = 0.f;
            const uvec4* wi = wi1t + tid;
            const float4* hv0 = (const float4*)h0s;
            #pragma unroll 8
            for (int kk = 0; kk < 32; ++kk) {
                uvec4 w = wi[(size_t)kk*1024];
                dot8m(a0, a1, w, hv0[kk*2], hv0[kk*2 + 1]);
            }
            const uvec4* wh = wh1t + tid;
            const float4* hv1 = (const float4*)h1s;
            #pragma unroll 8
            for (int kk = 0; kk < 32; ++kk) {
                uvec4 w = wh[(size_t)kk*1024];
                dot8m(a0, a1, w, hv1[kk*2], hv1[kk*2 + 1]);
            }
            red[tid] = a0 + a1;
        }
        __syncthreads();
        if (tid < 256) {
            float gi = red[tid], gf = red[HD+tid], gg = red[2*HD+tid], go = red[3*HD+tid];
            c1r = fsigm(gf)*c1r + fsigm(gi)*ftanh(gg);
            float h = fsigm(go)*ftanh(c1r);
            h1s[tid] = h;
            P.H1all[((size_t)t*BB + b)*HD + tid] = h;
        }
        __syncthreads();
    }
}

// ---------------- finalization: out = H1all @ WoutT + bout ----------------
// thread = 1 v-column, 32 rows; H-row operands are wave-uniform -> scalar loads.

__global__ __launch_bounds__(256)
void f2o(const float* __restrict__ H1all, const unsigned short* __restrict__ WoT8,
         const float* __restrict__ bout, float* __restrict__ out0) {
    int vt = blockIdx.x, rt = blockIdx.y, tid = threadIdx.x;
    int v = vt*256 + tid;
    const float* Hrow = H1all + (size_t)rt*32*HD;
    const uvec4* wt = (const uvec4*)WoT8;
    float acc[32];
    #pragma unroll
    for (int r = 0; r < 32; ++r) acc[r] = 0.f;
    for (int kk = 0; kk < 32; ++kk) {
        uvec4 w = wt[(size_t)kk*2048 + v];
        #pragma unroll
        for (int r = 0; r < 32; ++r) dot8s(acc[r], w, Hrow + r*HD + kk*8);
    }
    if (v < VV) {
        float bv = bout[v];
        #pragma unroll
        for (int r = 0; r < 32; ++r) {
            int row = rt*32 + r, tt = row >> 6, bb = row & 63;
            out0[((size_t)bb*TT + tt)*VV + v] = acc[r] + bv;
        }
    }
}

// ---------------- host ----------------

extern "C" void kernel_launch(void* const* d_in, const int* in_sizes, int n_in,
                              void* d_out, int out_size, void* d_ws, size_t ws_size,
                              hipStream_t stream) {
    const float* enc    = (const float*)d_in[0];
    const int*   caps   = (const int*)  d_in[1];
    const float* emb    = (const float*)d_in[2];
    const float* Wae    = (const float*)d_in[3];
    const float* bae    = (const float*)d_in[4];
    const float* Wad    = (const float*)d_in[5];
    const float* bad    = (const float*)d_in[6];
    const float* Wfa    = (const float*)d_in[7];
    const float* bfa    = (const float*)d_in[8];
    const float* Winith = (const float*)d_in[9];
    const float* binith = (const float*)d_in[10];
    const float* Winitc = (const float*)d_in[11];
    const float* binitc = (const float*)d_in[12];
    const float* Wih0   = (const float*)d_in[13];
    const float* Whh0   = (const float*)d_in[14];
    const float* bih0   = (const float*)d_in[15];
    const float* bhh0   = (const float*)d_in[16];
    const float* Wih1   = (const float*)d_in[17];
    const float* Whh1   = (const float*)d_in[18];
    const float* bih1   = (const float*)d_in[19];
    const float* bhh1   = (const float*)d_in[20];
    const float* Wout   = (const float*)d_in[21];
    const float* bout   = (const float*)d_in[22];

    // workspace layout (float units)
    float* ws = (float*)d_ws;
    unsigned short* att1T8 = (unsigned short*)(ws);             // 8,388,608 ush
    unsigned short* encP   = (unsigned short*)(ws + 4194304);   // 8,388,608 ush
    float* H1all = ws + 8388608;                                // 4,194,304 f
    unsigned short* Wih0T8 = (unsigned short*)(ws + 12582912);  //   524,288 ush
    unsigned short* Whh0T8 = (unsigned short*)(ws + 12845056);  //   262,144 ush
    unsigned short* Wih1T8 = (unsigned short*)(ws + 12976128);  //   262,144 ush
    unsigned short* Whh1T8 = (unsigned short*)(ws + 13107200);  //   262,144 ush
    unsigned short* WadT8  = (unsigned short*)(ws + 13238272);  //    65,536 ush
    float* meanb = ws + 13271040;
    float* h0g   = ws + 13287424;
    float* c0g   = ws + 13303808;
    float* h1g   = ws + 13320192;
    float* c1g   = ws + 13336576;
    unsigned short* E = (unsigned short*)(ws + 13352960);       // 16,777,216 ush (optional)

    const int useE = (ws_size >= (size_t)(13352960 + 8388608) * 4) ? 1 : 0;
    // WoutT8: 524,288 ush = 262,144 floats
    const int useWtail = (ws_size >= (size_t)(13352960 + 8388608 + 262144) * 4) ? 1 : 0;
    unsigned short* WoT8 = useWtail ? (unsigned short*)(ws + 13352960 + 8388608)
                                    : att1T8;   // reuse att1 region after main64

    float* out0  = (float*)d_out;
    float* wsout = out0 + (size_t)BB*TT*VV;

    hipLaunchKernelGGL(k_mean,   dim3(BB),     dim3(256), 0, stream, enc, meanb);
    hipLaunchKernelGGL(k_init,   dim3(BB),     dim3(256), 0, stream, meanb, Winith, binith,
                       Winitc, binitc, h0g, c0g, h1g, c1g);
    hipLaunchKernelGGL(k_att1T8, dim3(16, BB), dim3(512), 0, stream, enc, Wae, bae, att1T8);
    hipLaunchKernelGGL(k_encP,   dim3(BB, 16), dim3(256), 0, stream, enc, encP);
    hipLaunchKernelGGL(k_cvtT8,  dim3(256),    dim3(256), 0, stream, Wih0, Wih0T8, 10, 64, 1.0f);
    hipLaunchKernelGGL(k_cvtT8,  dim3(128),    dim3(256), 0, stream, Whh0, Whh0T8, 10, 32, 1.0f);
    hipLaunchKernelGGL(k_cvtT8,  dim3(128),    dim3(256), 0, stream, Wih1, Wih1T8, 10, 32, 1.0f);
    hipLaunchKernelGGL(k_cvtT8,  dim3(128),    dim3(256), 0, stream, Whh1, Whh1T8, 10, 32, 1.0f);
    hipLaunchKernelGGL(k_cvtT8,  dim3(32),     dim3(256), 0, stream, Wad,  WadT8,   8, 32, S2L);
    if (useE)
        hipLaunchKernelGGL(k_E,  dim3(BB, 16), dim3(1024), 0, stream, caps, emb, Wih0T8, E);
    if (useWtail)
        hipLaunchKernelGGL(k_cvtW, dim3(256),  dim3(256), 0, stream, Wout, WoT8);

    KP2 kp;
    kp.caps = caps; kp.emb = emb;
    kp.Wfa = Wfa; kp.bfa = bfa; kp.bad = bad;
    kp.bih0 = bih0; kp.bhh0 = bhh0; kp.bih1 = bih1; kp.bhh1 = bhh1;
    kp.WadT8 = WadT8; kp.Wih0T8 = Wih0T8; kp.Whh0T8 = Whh0T8; kp.Wih1T8 = Wih1T8; kp.Whh1T8 = Whh1T8;
    kp.att1T8 = att1T8; kp.encP = encP; kp.E = E;
    kp.h0g = h0g; kp.c0g = c0g; kp.h1g = h1g; kp.c1g = c1g;
    kp.H1all = H1all; kp.wsout = wsout;

    if (useE)
        hipLaunchKernelGGL((main64<1>), dim3(BB), dim3(1024), 0, stream, kp);
    else
        hipLaunchKernelGGL((main64<0>), dim3(BB), dim3(1024), 0, stream, kp);

    if (!useWtail)
        hipLaunchKernelGGL(k_cvtW, dim3(256),  dim3(256), 0, stream, Wout, WoT8);

    hipLaunchKernelGGL(f2o, dim3(8, 512), dim3(256), 0, stream, H1all, WoT8, bout, out0);
}